// Round 1
// baseline (2574.972 us; speedup 1.0000x reference)
//
#include <hip/hip_runtime.h>
#include <math.h>

#define BB 16
#define CC 256
#define C2 128
#define NN 2048

// workspace layout (float offsets)
#define OFF_XQ   ((size_t)0)
#define OFF_XK   (OFF_XQ + (size_t)BB*C2*NN)   // 4194304
#define OFF_XV   (OFF_XK + (size_t)BB*C2*NN)   // 8388608
#define OFF_X2   (OFF_XV + (size_t)BB*CC*NN)   // 16777216
#define OFF_Y    (OFF_X2 + (size_t)BB*CC*NN)   // 25165824
#define OFF_RMAX (OFF_Y  + (size_t)BB*CC*NN)   // 33554432
#define OFF_RSUM (OFF_RMAX + (size_t)BB*NN)
#define OFF_S    (OFF_RSUM + (size_t)BB*NN)
#define OFF_D    OFF_XQ   // aliases xq+xk (dead by the time d is written)

// out[b,o,n] = sum_c W[o,c] * in[b,c,n] + bias[o]
__global__ __launch_bounds__(256) void conv1x1_kernel(
    const float* __restrict__ in, const float* __restrict__ W,
    const float* __restrict__ bias, float* __restrict__ out,
    int Cin, int Cout)
{
    int n  = blockIdx.x * 256 + threadIdx.x;
    int o0 = blockIdx.y * 4;
    int b  = blockIdx.z;
    const float* ip = in + (size_t)b * Cin * NN + n;
    const float* w0 = W + (size_t)o0 * Cin;
    float a0 = bias ? bias[o0+0] : 0.f;
    float a1 = bias ? bias[o0+1] : 0.f;
    float a2 = bias ? bias[o0+2] : 0.f;
    float a3 = bias ? bias[o0+3] : 0.f;
    for (int c = 0; c < Cin; ++c) {
        float v = ip[(size_t)c * NN];
        a0 = fmaf(w0[c],         v, a0);
        a1 = fmaf(w0[Cin + c],   v, a1);
        a2 = fmaf(w0[2*Cin + c], v, a2);
        a3 = fmaf(w0[3*Cin + c], v, a3);
    }
    float* op = out + ((size_t)b * Cout + o0) * NN + n;
    op[0] = a0; op[NN] = a1; op[2*NN] = a2; op[3*NN] = a3;
}

// Pass 1: per-row (n) max and sum of exp of energy e[n,m] = sum_c xq[b,c,n]*xk[b,c,m]
__global__ __launch_bounds__(256) void rowstats_kernel(
    const float* __restrict__ xq, const float* __restrict__ xk,
    float* __restrict__ rmax, float* __restrict__ rsum)
{
    __shared__ float xq_s[C2][32];
    __shared__ float xk_s[C2][64];
    __shared__ float e_s[32][65];
    __shared__ float Mrow[32], Srow[32];
    const int tid = threadIdx.x;
    const int b  = blockIdx.y;
    const int n0 = blockIdx.x * 32;
    const float* xqb = xq + (size_t)b * C2 * NN;
    const float* xkb = xk + (size_t)b * C2 * NN;
    for (int i = tid; i < C2*32; i += 256) {
        int c = i >> 5, j = i & 31;
        xq_s[c][j] = xqb[(size_t)c * NN + n0 + j];
    }
    if (tid < 32) { Mrow[tid] = -1e30f; Srow[tid] = 0.f; }
    __syncthreads();
    const int n = tid & 31, mg = tid >> 5;
    for (int m0 = 0; m0 < NN; m0 += 64) {
        for (int i = tid; i < C2*64; i += 256) {
            int c = i >> 6, m = i & 63;
            xk_s[c][m] = xkb[(size_t)c * NN + m0 + m];
        }
        __syncthreads();
        float e0=0,e1=0,e2=0,e3=0,e4=0,e5=0,e6=0,e7=0;
        #pragma unroll 4
        for (int c = 0; c < C2; ++c) {
            float a = xq_s[c][n];
            float4 p0 = *(const float4*)&xk_s[c][mg*8];
            float4 p1 = *(const float4*)&xk_s[c][mg*8+4];
            e0 = fmaf(a, p0.x, e0); e1 = fmaf(a, p0.y, e1);
            e2 = fmaf(a, p0.z, e2); e3 = fmaf(a, p0.w, e3);
            e4 = fmaf(a, p1.x, e4); e5 = fmaf(a, p1.y, e5);
            e6 = fmaf(a, p1.z, e6); e7 = fmaf(a, p1.w, e7);
        }
        e_s[n][mg*8+0]=e0; e_s[n][mg*8+1]=e1; e_s[n][mg*8+2]=e2; e_s[n][mg*8+3]=e3;
        e_s[n][mg*8+4]=e4; e_s[n][mg*8+5]=e5; e_s[n][mg*8+6]=e6; e_s[n][mg*8+7]=e7;
        __syncthreads();
        if (tid < 32) {
            float M = Mrow[tid];
            float mx = M;
            #pragma unroll 8
            for (int k = 0; k < 64; ++k) mx = fmaxf(mx, e_s[tid][k]);
            float s = Srow[tid] * __expf(M - mx);
            #pragma unroll 8
            for (int k = 0; k < 64; ++k) s += __expf(e_s[tid][k] - mx);
            Mrow[tid] = mx; Srow[tid] = s;
        }
        __syncthreads();
    }
    if (tid < 32) {
        rmax[(size_t)b * NN + n0 + tid] = Mrow[tid];
        rsum[(size_t)b * NN + n0 + tid] = Srow[tid];
    }
}

// Pass 2: for a 32-column m-tile, recompute energy, P = exp(e - M[n]) / S[n],
// accumulate y[c,m] = sum_n xv[c,n] * P[n,m] and s[m] = colsum(P).
__global__ __launch_bounds__(256) void pv_kernel(
    const float* __restrict__ xq, const float* __restrict__ xk,
    const float* __restrict__ xv, const float* __restrict__ rmax,
    const float* __restrict__ rsum, float* __restrict__ y,
    float* __restrict__ s_out)
{
    __shared__ float xk_s[C2][32];
    __shared__ float xq_s[C2][32];
    __shared__ float xv_s[CC][33];
    __shared__ float p_s[32][36];
    __shared__ float M_s[32], Si_s[32], s_acc[32];
    const int tid = threadIdx.x;
    const int b  = blockIdx.y;
    const int m0 = blockIdx.x * 32;
    const float* xqb = xq + (size_t)b * C2 * NN;
    const float* xkb = xk + (size_t)b * C2 * NN;
    const float* xvb = xv + (size_t)b * CC * NN;
    for (int i = tid; i < C2*32; i += 256) {
        int c = i >> 5, m = i & 31;
        xk_s[c][m] = xkb[(size_t)c * NN + m0 + m];
    }
    if (tid < 32) s_acc[tid] = 0.f;
    float acc[8][4];
    #pragma unroll
    for (int i = 0; i < 8; ++i)
        { acc[i][0]=0.f; acc[i][1]=0.f; acc[i][2]=0.f; acc[i][3]=0.f; }
    const int en = tid & 31, emg = tid >> 5;  // energy: m = emg*4 + j
    const int mt = tid & 7,  ct  = tid >> 3;  // PV: c = ct*8+ci, m = mt*4+mi
    __syncthreads();
    for (int n0 = 0; n0 < NN; n0 += 32) {
        for (int i = tid; i < C2*32; i += 256) {
            int c = i >> 5, j = i & 31;
            xq_s[c][j] = xqb[(size_t)c * NN + n0 + j];
        }
        for (int i = tid; i < CC*32; i += 256) {
            int c = i >> 5, k = i & 31;
            xv_s[c][k] = xvb[(size_t)c * NN + n0 + k];
        }
        if (tid < 32) {
            M_s[tid]  = rmax[(size_t)b * NN + n0 + tid];
            Si_s[tid] = 1.f / rsum[(size_t)b * NN + n0 + tid];
        }
        __syncthreads();
        float e0=0,e1=0,e2=0,e3=0;
        #pragma unroll 4
        for (int c = 0; c < C2; ++c) {
            float a = xq_s[c][en];
            float4 kk = *(const float4*)&xk_s[c][emg*4];
            e0 = fmaf(a, kk.x, e0); e1 = fmaf(a, kk.y, e1);
            e2 = fmaf(a, kk.z, e2); e3 = fmaf(a, kk.w, e3);
        }
        float Mn = M_s[en], Si = Si_s[en];
        p_s[en][emg*4+0] = __expf(e0 - Mn) * Si;
        p_s[en][emg*4+1] = __expf(e1 - Mn) * Si;
        p_s[en][emg*4+2] = __expf(e2 - Mn) * Si;
        p_s[en][emg*4+3] = __expf(e3 - Mn) * Si;
        __syncthreads();
        if (tid < 32) {
            float ss = 0.f;
            #pragma unroll 8
            for (int k = 0; k < 32; ++k) ss += p_s[k][tid];
            s_acc[tid] += ss;
        }
        #pragma unroll 2
        for (int k = 0; k < 32; ++k) {
            float4 pp = *(const float4*)&p_s[k][mt*4];
            #pragma unroll
            for (int ci = 0; ci < 8; ++ci) {
                float a = xv_s[ct*8+ci][k];
                acc[ci][0] = fmaf(a, pp.x, acc[ci][0]);
                acc[ci][1] = fmaf(a, pp.y, acc[ci][1]);
                acc[ci][2] = fmaf(a, pp.z, acc[ci][2]);
                acc[ci][3] = fmaf(a, pp.w, acc[ci][3]);
            }
        }
        __syncthreads();
    }
    float* yb = y + (size_t)b * CC * NN + m0;
    #pragma unroll
    for (int ci = 0; ci < 8; ++ci) {
        float4 v; v.x = acc[ci][0]; v.y = acc[ci][1]; v.z = acc[ci][2]; v.w = acc[ci][3];
        *(float4*)&yb[(size_t)(ct*8+ci) * NN + mt*4] = v;
    }
    if (tid < 32) s_out[(size_t)b * NN + m0 + tid] = s_acc[tid];
}

// d = x2 - y / (1e-9 + s[b,n])
__global__ __launch_bounds__(256) void dcalc_kernel(
    const float* __restrict__ x2, const float* __restrict__ y,
    const float* __restrict__ s, float* __restrict__ d)
{
    size_t total = (size_t)BB * CC * NN;
    for (size_t idx = (size_t)blockIdx.x * 256 + threadIdx.x; idx < total;
         idx += (size_t)gridDim.x * 256) {
        int n  = (int)(idx & (NN - 1));
        int bc = (int)(idx >> 11);
        int b  = bc >> 8;
        float sv = s[(size_t)b * NN + n];
        d[idx] = x2[idx] - y[idx] * (1.f / (1e-9f + sv));
    }
}

// t = Wt @ d + bt;  bn = t*inv + (beta - mean*inv);  out = relu(bn) + x2
__global__ __launch_bounds__(256) void final_kernel(
    const float* __restrict__ d, const float* __restrict__ x2,
    const float* __restrict__ Wt, const float* __restrict__ bt,
    const float* __restrict__ gamma, const float* __restrict__ beta,
    const float* __restrict__ rmean, const float* __restrict__ rvar,
    float* __restrict__ out)
{
    int n  = blockIdx.x * 256 + threadIdx.x;
    int o0 = blockIdx.y * 4;
    int b  = blockIdx.z;
    const float* dp = d + (size_t)b * CC * NN + n;
    const float* w0 = Wt + (size_t)o0 * CC;
    float a0 = bt[o0+0], a1 = bt[o0+1], a2 = bt[o0+2], a3 = bt[o0+3];
    for (int c = 0; c < CC; ++c) {
        float v = dp[(size_t)c * NN];
        a0 = fmaf(w0[c],        v, a0);
        a1 = fmaf(w0[CC + c],   v, a1);
        a2 = fmaf(w0[2*CC + c], v, a2);
        a3 = fmaf(w0[3*CC + c], v, a3);
    }
    float accs[4] = {a0, a1, a2, a3};
    size_t obase = ((size_t)b * CC + o0) * NN + n;
    #pragma unroll
    for (int j = 0; j < 4; ++j) {
        int o = o0 + j;
        float inv = gamma[o] * rsqrtf(rvar[o] + 1e-5f);
        float add = beta[o] - rmean[o] * inv;
        float t = accs[j] * inv + add;
        float xx = x2[obase + (size_t)j * NN];
        out[obase + (size_t)j * NN] = fmaxf(t, 0.f) + xx;
    }
}

extern "C" void kernel_launch(void* const* d_in, const int* in_sizes, int n_in,
                              void* d_out, int out_size, void* d_ws, size_t ws_size,
                              hipStream_t stream)
{
    const float* q     = (const float*)d_in[0];
    const float* x     = (const float*)d_in[1];
    const float* Wq    = (const float*)d_in[2];
    const float* Wk    = (const float*)d_in[3];
    const float* Wv    = (const float*)d_in[4];
    const float* bv    = (const float*)d_in[5];
    const float* Wt    = (const float*)d_in[6];
    const float* bt    = (const float*)d_in[7];
    const float* gamma = (const float*)d_in[8];
    const float* beta  = (const float*)d_in[9];
    const float* rmean = (const float*)d_in[10];
    const float* rvar  = (const float*)d_in[11];
    float* out = (float*)d_out;
    float* ws  = (float*)d_ws;

    float* xq   = ws + OFF_XQ;
    float* xk   = ws + OFF_XK;
    float* xv   = ws + OFF_XV;
    float* x2   = ws + OFF_X2;
    float* yb   = ws + OFF_Y;
    float* rmax = ws + OFF_RMAX;
    float* rsum = ws + OFF_RSUM;
    float* sb   = ws + OFF_S;
    float* dbuf = ws + OFF_D;   // aliases xq+xk (both dead after pv_kernel)

    dim3 blk(256);
    conv1x1_kernel<<<dim3(NN/256, C2/4, BB), blk, 0, stream>>>(q, Wq, nullptr, xq, C2, C2);
    conv1x1_kernel<<<dim3(NN/256, C2/4, BB), blk, 0, stream>>>(x, Wk, nullptr, xk, C2, C2);
    conv1x1_kernel<<<dim3(NN/256, CC/4, BB), blk, 0, stream>>>(q, Wv, bv, xv, C2, CC);
    conv1x1_kernel<<<dim3(NN/256, CC/4, BB), blk, 0, stream>>>(x, Wv, bv, x2, C2, CC);
    rowstats_kernel<<<dim3(NN/32, BB), blk, 0, stream>>>(xq, xk, rmax, rsum);
    pv_kernel<<<dim3(NN/32, BB), blk, 0, stream>>>(xq, xk, xv, rmax, rsum, yb, sb);
    dcalc_kernel<<<dim3(4096), blk, 0, stream>>>(x2, yb, sb, dbuf);
    final_kernel<<<dim3(NN/256, CC/4, BB), blk, 0, stream>>>(dbuf, x2, Wt, bt, gamma, beta,
                                                             rmean, rvar, out);
}

// Round 4
// 514.488 us; speedup vs baseline: 5.0049x; 5.0049x over previous
//
#include <hip/hip_runtime.h>
#include <hip/hip_bf16.h>
#include <math.h>

#define BB 16
#define CC 256
#define C2 128
#define NN 2048

typedef __attribute__((ext_vector_type(8))) _Float16 f16x8;
typedef __attribute__((ext_vector_type(8))) short bf16x8;
typedef __attribute__((ext_vector_type(16))) float f32x16;
typedef unsigned short u16;

// ---- workspace layout ----
// float region:
//   OFF_X2 = 0              : x2 fp32 [B][C][N]        (8388608 floats)
//   OFF_Y  = 8388608        : y  fp32 [B][C][N]        (8388608 floats)  (d in-place)
//   u16 region starts at float offset 16777216:
//     XQT fp16 [B][N][C2]   u16 off 0        (4194304)
//     XKT fp16 [B][N][C2]   u16 off 4194304  (4194304)
//     XV  bf16 [B][C][N]    u16 off 8388608  (8388608)
//   stats (floats) at float offset 25165824: RMAX, RSUM, S (32768 each)
#define OFF_X2   ((size_t)0)
#define OFF_Y    ((size_t)8388608)
#define OFF_BF16 ((size_t)16777216)   // float offset where u16 region starts
#define UOFF_XQT ((size_t)0)
#define UOFF_XKT ((size_t)4194304)
#define UOFF_XV  ((size_t)8388608)
#define OFF_RMAX ((size_t)25165824)
#define OFF_RSUM (OFF_RMAX + 32768)
#define OFF_S    (OFF_RSUM + 32768)

// fp16 conversions: used ONLY for xq/xk (values ~N(0,1), in-range).
__device__ __forceinline__ u16 f2h(float f) {
    union { _Float16 h; u16 u; } v; v.h = (_Float16)f;  // RTE
    return v.u;
}
// bf16 conversions: used for xv and P (P spans 1e-33..1 — needs fp32-like range).
__device__ __forceinline__ u16 f2bf(float f) {
    union { float f; unsigned u; } v; v.f = f;
    return (u16)((v.u + 0x7fffu + ((v.u >> 16) & 1u)) >> 16);
}
__device__ __forceinline__ float bf2f(u16 h) {
    union { unsigned u; float f; } v; v.u = ((unsigned)h) << 16;
    return v.f;
}

// xq/xk projection: out transposed fp16 [b][n][o] (o contiguous)
__global__ __launch_bounds__(256) void conv_qk_kernel(
    const float* __restrict__ in, const float* __restrict__ W,
    u16* __restrict__ outT)
{
    int n  = blockIdx.x * 256 + threadIdx.x;
    int o0 = blockIdx.y * 8;
    int b  = blockIdx.z;
    const float* ip = in + (size_t)b * C2 * NN + n;
    const float* w  = W + (size_t)o0 * C2;
    float a[8];
    #pragma unroll
    for (int j = 0; j < 8; ++j) a[j] = 0.f;
    for (int c = 0; c < C2; ++c) {
        float v = ip[(size_t)c * NN];
        #pragma unroll
        for (int j = 0; j < 8; ++j) a[j] = fmaf(w[j * C2 + c], v, a[j]);
    }
    union { u16 h[8]; uint4 v4; } pk;
    #pragma unroll
    for (int j = 0; j < 8; ++j) pk.h[j] = f2h(a[j]);
    *(uint4*)&outT[((size_t)b * NN + n) * C2 + o0] = pk.v4;
}

// v projection of q: out bf16 [b][o][n]
__global__ __launch_bounds__(256) void conv_v_bf16_kernel(
    const float* __restrict__ in, const float* __restrict__ W,
    const float* __restrict__ bias, u16* __restrict__ out)
{
    int n  = blockIdx.x * 256 + threadIdx.x;
    int o0 = blockIdx.y * 8;
    int b  = blockIdx.z;
    const float* ip = in + (size_t)b * C2 * NN + n;
    const float* w  = W + (size_t)o0 * C2;
    float a[8];
    #pragma unroll
    for (int j = 0; j < 8; ++j) a[j] = bias[o0 + j];
    for (int c = 0; c < C2; ++c) {
        float v = ip[(size_t)c * NN];
        #pragma unroll
        for (int j = 0; j < 8; ++j) a[j] = fmaf(w[j * C2 + c], v, a[j]);
    }
    u16* op = out + ((size_t)b * CC + o0) * NN + n;
    #pragma unroll
    for (int j = 0; j < 8; ++j) op[(size_t)j * NN] = f2bf(a[j]);
}

// v projection of x: out fp32 [b][o][n]  (x2, needed exactly for residual)
__global__ __launch_bounds__(256) void conv_v_f32_kernel(
    const float* __restrict__ in, const float* __restrict__ W,
    const float* __restrict__ bias, float* __restrict__ out)
{
    int n  = blockIdx.x * 256 + threadIdx.x;
    int o0 = blockIdx.y * 8;
    int b  = blockIdx.z;
    const float* ip = in + (size_t)b * C2 * NN + n;
    const float* w  = W + (size_t)o0 * C2;
    float a[8];
    #pragma unroll
    for (int j = 0; j < 8; ++j) a[j] = bias[o0 + j];
    for (int c = 0; c < C2; ++c) {
        float v = ip[(size_t)c * NN];
        #pragma unroll
        for (int j = 0; j < 8; ++j) a[j] = fmaf(w[j * C2 + c], v, a[j]);
    }
    float* op = out + ((size_t)b * CC + o0) * NN + n;
    #pragma unroll
    for (int j = 0; j < 8; ++j) op[(size_t)j * NN] = a[j];
}

// Pass 1: per-n row max / sumexp of E[n,m] = sum_c xq[c,n] xk[c,m], via fp16 MFMA.
// Computes E_t[m][n] tiles: A = xkT (m rows), B = xqT (n cols), K = C2.
__global__ __launch_bounds__(256) void rowstats_mfma(
    const u16* __restrict__ xqT, const u16* __restrict__ xkT,
    float* __restrict__ rmax, float* __restrict__ rsum)
{
    __shared__ u16 xq_s[64 * 136];
    __shared__ u16 xk_s[64 * 136];
    __shared__ float Mp[4][32];
    __shared__ float Sp[4][32];
    const int tid  = threadIdx.x;
    const int b    = blockIdx.y;
    const int n0   = blockIdx.x * 64;
    const int lane = tid & 63;
    const int wave = tid >> 6;
    const u16* xqb = xqT + (size_t)b * NN * C2;
    const u16* xkb = xkT + (size_t)b * NN * C2;

    for (int i = tid; i < 64 * 16; i += 256) {
        int r = i >> 4, c8 = i & 15;
        *(uint4*)&xq_s[r * 136 + c8 * 8] =
            *(const uint4*)&xqb[(size_t)(n0 + r) * C2 + c8 * 8];
    }
    const int msub = wave >> 1, nsub = wave & 1;
    const int lrow = lane & 31;
    const int lk8  = (lane >> 5) * 8;
    float runM = -1e30f, runS = 0.f;

    for (int m0 = 0; m0 < NN; m0 += 64) {
        for (int i = tid; i < 64 * 16; i += 256) {
            int r = i >> 4, c8 = i & 15;
            *(uint4*)&xk_s[r * 136 + c8 * 8] =
                *(const uint4*)&xkb[(size_t)(m0 + r) * C2 + c8 * 8];
        }
        __syncthreads();
        f32x16 e;
        #pragma unroll
        for (int r = 0; r < 16; ++r) e[r] = 0.f;
        const u16* arow = &xk_s[(msub * 32 + lrow) * 136 + lk8];
        const u16* brow = &xq_s[(nsub * 32 + lrow) * 136 + lk8];
        #pragma unroll
        for (int kk = 0; kk < 8; ++kk) {
            f16x8 a  = *(const f16x8*)&arow[kk * 16];
            f16x8 bb = *(const f16x8*)&brow[kk * 16];
            e = __builtin_amdgcn_mfma_f32_32x32x16_f16(a, bb, e, 0, 0, 0);
        }
        float tm = e[0];
        #pragma unroll
        for (int r = 1; r < 16; ++r) tm = fmaxf(tm, e[r]);
        float newM = fmaxf(runM, tm);
        float sc = __expf(runM - newM);
        float ts = 0.f;
        #pragma unroll
        for (int r = 0; r < 16; ++r) ts += __expf(e[r] - newM);
        runS = runS * sc + ts;
        runM = newM;
        __syncthreads();
    }
    float oM = __shfl_xor(runM, 32, 64);
    float oS = __shfl_xor(runS, 32, 64);
    float M2 = fmaxf(runM, oM);
    float S2 = runS * __expf(runM - M2) + oS * __expf(oM - M2);
    if (lane < 32) { Mp[wave][lane] = M2; Sp[wave][lane] = S2; }
    __syncthreads();
    if (tid < 64) {
        int ns = tid >> 5, li = tid & 31;
        float Ma = Mp[ns][li], Mb = Mp[ns + 2][li];
        float Mf = fmaxf(Ma, Mb);
        float Sf = Sp[ns][li] * __expf(Ma - Mf) + Sp[ns + 2][li] * __expf(Mb - Mf);
        rmax[(size_t)b * NN + n0 + tid] = Mf;
        rsum[(size_t)b * NN + n0 + tid] = Sf;
    }
}

// Pass 2: per 64-col m-tile, recompute E_t (fp16 MFMA, bitwise-identical to pass 1),
// P = exp(e-M)/S stored as bf16 (range!), y[c,m] += xv[c,n] P[n,m] via bf16 MFMA;
// s[m] = colsum(P) from the same bf16 P the PV consumes.
__global__ __launch_bounds__(256) void pv_mfma(
    const u16* __restrict__ xqT, const u16* __restrict__ xkT,
    const u16* __restrict__ xv, const float* __restrict__ rmax,
    const float* __restrict__ rsum, float* __restrict__ y,
    float* __restrict__ s_out)
{
    __shared__ u16 xk_s[64 * 136];   // [m][c]  fp16
    __shared__ u16 xq_s[64 * 136];   // [n][c]  fp16
    __shared__ u16 xv_s[256 * 72];   // [c][n]  bf16
    __shared__ u16 p_s[64 * 72];     // [m][n]  bf16
    __shared__ float M_s[64];
    __shared__ float Si_s[64];
    const int tid  = threadIdx.x;
    const int b    = blockIdx.y;
    const int m0   = blockIdx.x * 64;
    const int lane = tid & 63;
    const int wave = tid >> 6;
    const u16* xqb = xqT + (size_t)b * NN * C2;
    const u16* xkb = xkT + (size_t)b * NN * C2;
    const u16* xvb = xv + (size_t)b * CC * NN;

    for (int i = tid; i < 64 * 16; i += 256) {
        int r = i >> 4, c8 = i & 15;
        *(uint4*)&xk_s[r * 136 + c8 * 8] =
            *(const uint4*)&xkb[(size_t)(m0 + r) * C2 + c8 * 8];
    }
    f32x16 acc00, acc01, acc10, acc11;
    #pragma unroll
    for (int r = 0; r < 16; ++r)
        { acc00[r] = 0.f; acc01[r] = 0.f; acc10[r] = 0.f; acc11[r] = 0.f; }
    float s_reg = 0.f;
    const int lrow  = lane & 31;
    const int lk8   = (lane >> 5) * 8;
    const int emsub = wave & 1, ensub = wave >> 1;
    const int cbase = wave * 64;
    const int smq   = tid & 63, sq = tid >> 6;

    for (int n0 = 0; n0 < NN; n0 += 64) {
        for (int i = tid; i < 64 * 16; i += 256) {
            int r = i >> 4, c8 = i & 15;
            *(uint4*)&xq_s[r * 136 + c8 * 8] =
                *(const uint4*)&xqb[(size_t)(n0 + r) * C2 + c8 * 8];
        }
        for (int i = tid; i < 256 * 8; i += 256) {
            int c = i >> 3, k8 = i & 7;
            *(uint4*)&xv_s[c * 72 + k8 * 8] =
                *(const uint4*)&xvb[(size_t)c * NN + n0 + k8 * 8];
        }
        if (tid < 64) {
            M_s[tid]  = rmax[(size_t)b * NN + n0 + tid];
            Si_s[tid] = 1.f / rsum[(size_t)b * NN + n0 + tid];
        }
        __syncthreads();
        // energy subtile (32x32) per wave — fp16, same fragments/order as pass 1
        f32x16 e;
        #pragma unroll
        for (int r = 0; r < 16; ++r) e[r] = 0.f;
        {
            const u16* arow = &xk_s[(emsub * 32 + lrow) * 136 + lk8];
            const u16* brow = &xq_s[(ensub * 32 + lrow) * 136 + lk8];
            #pragma unroll
            for (int kk = 0; kk < 8; ++kk) {
                f16x8 a  = *(const f16x8*)&arow[kk * 16];
                f16x8 bb = *(const f16x8*)&brow[kk * 16];
                e = __builtin_amdgcn_mfma_f32_32x32x16_f16(a, bb, e, 0, 0, 0);
            }
        }
        {
            int nl = ensub * 32 + lrow;
            float Mn = M_s[nl], Si = Si_s[nl];
            int mbase = emsub * 32 + 4 * (lane >> 5);
            #pragma unroll
            for (int r = 0; r < 16; ++r) {
                int ml = mbase + (r & 3) + 8 * (r >> 2);
                float p = __expf(e[r] - Mn) * Si;
                p_s[ml * 72 + nl] = f2bf(p);
            }
        }
        __syncthreads();
        // colsum partial (reads the same bf16 P that PV consumes)
        {
            const u16* pr = &p_s[smq * 72 + sq * 16];
            float ss = 0.f;
            #pragma unroll
            for (int j = 0; j < 16; ++j) ss += bf2f(pr[j]);
            s_reg += ss;
        }
        // PV: per wave, c-rows [cbase, cbase+64), both 32-col m-subtiles — bf16 MFMA
        {
            const u16* a0r = &xv_s[(cbase + lrow) * 72 + lk8];
            const u16* a1r = &xv_s[(cbase + 32 + lrow) * 72 + lk8];
            const u16* b0r = &p_s[lrow * 72 + lk8];
            const u16* b1r = &p_s[(32 + lrow) * 72 + lk8];
            #pragma unroll
            for (int kk = 0; kk < 4; ++kk) {
                bf16x8 a0 = *(const bf16x8*)&a0r[kk * 16];
                bf16x8 a1 = *(const bf16x8*)&a1r[kk * 16];
                bf16x8 b0 = *(const bf16x8*)&b0r[kk * 16];
                bf16x8 b1 = *(const bf16x8*)&b1r[kk * 16];
                acc00 = __builtin_amdgcn_mfma_f32_32x32x16_bf16(a0, b0, acc00, 0, 0, 0);
                acc01 = __builtin_amdgcn_mfma_f32_32x32x16_bf16(a0, b1, acc01, 0, 0, 0);
                acc10 = __builtin_amdgcn_mfma_f32_32x32x16_bf16(a1, b0, acc10, 0, 0, 0);
                acc11 = __builtin_amdgcn_mfma_f32_32x32x16_bf16(a1, b1, acc11, 0, 0, 0);
            }
        }
        __syncthreads();
    }
    float* yb = y + (size_t)b * CC * NN;
    #pragma unroll
    for (int r = 0; r < 16; ++r) {
        int ro = (r & 3) + 8 * (r >> 2) + 4 * (lane >> 5);
        yb[(size_t)(cbase + ro) * NN + m0 + lrow]           = acc00[r];
        yb[(size_t)(cbase + ro) * NN + m0 + 32 + lrow]      = acc01[r];
        yb[(size_t)(cbase + 32 + ro) * NN + m0 + lrow]      = acc10[r];
        yb[(size_t)(cbase + 32 + ro) * NN + m0 + 32 + lrow] = acc11[r];
    }
    __syncthreads();
    float* s_part = (float*)p_s;   // p_s dead now
    s_part[(tid & 63) * 4 + (tid >> 6)] = s_reg;
    __syncthreads();
    if (tid < 64) {
        float ss = s_part[tid * 4] + s_part[tid * 4 + 1] +
                   s_part[tid * 4 + 2] + s_part[tid * 4 + 3];
        s_out[(size_t)b * NN + m0 + tid] = ss;
    }
}

// d = x2 - y / (1e-9 + s[b,m])   (in-place into y)
__global__ __launch_bounds__(256) void dcalc_kernel(
    const float* __restrict__ x2, float* __restrict__ y,
    const float* __restrict__ s)
{
    size_t total = (size_t)BB * CC * NN;
    for (size_t idx = (size_t)blockIdx.x * 256 + threadIdx.x; idx < total;
         idx += (size_t)gridDim.x * 256) {
        int n = (int)(idx & (NN - 1));
        int b = (int)(idx >> 19);   // CC*NN = 2^19
        float sv = s[(size_t)b * NN + n];
        y[idx] = x2[idx] - y[idx] * (1.f / (1e-9f + sv));
    }
}

// t = Wt @ d + bt;  bn = t*inv + (beta - mean*inv);  out = relu(bn) + x2
__global__ __launch_bounds__(256) void final_kernel(
    const float* __restrict__ d, const float* __restrict__ x2,
    const float* __restrict__ Wt, const float* __restrict__ bt,
    const float* __restrict__ gamma, const float* __restrict__ beta,
    const float* __restrict__ rmean, const float* __restrict__ rvar,
    float* __restrict__ out)
{
    int n  = blockIdx.x * 256 + threadIdx.x;
    int o0 = blockIdx.y * 8;
    int b  = blockIdx.z;
    const float* dp = d + (size_t)b * CC * NN + n;
    const float* w  = Wt + (size_t)o0 * CC;
    float a[8];
    #pragma unroll
    for (int j = 0; j < 8; ++j) a[j] = bt[o0 + j];
    for (int c = 0; c < CC; ++c) {
        float v = dp[(size_t)c * NN];
        #pragma unroll
        for (int j = 0; j < 8; ++j) a[j] = fmaf(w[j * CC + c], v, a[j]);
    }
    size_t obase = ((size_t)b * CC + o0) * NN + n;
    #pragma unroll
    for (int j = 0; j < 8; ++j) {
        int o = o0 + j;
        float inv = gamma[o] * rsqrtf(rvar[o] + 1e-5f);
        float add = beta[o] - rmean[o] * inv;
        float t = a[j] * inv + add;
        float xx = x2[obase + (size_t)j * NN];
        out[obase + (size_t)j * NN] = fmaxf(t, 0.f) + xx;
    }
}

extern "C" void kernel_launch(void* const* d_in, const int* in_sizes, int n_in,
                              void* d_out, int out_size, void* d_ws, size_t ws_size,
                              hipStream_t stream)
{
    const float* q     = (const float*)d_in[0];
    const float* x     = (const float*)d_in[1];
    const float* Wq    = (const float*)d_in[2];
    const float* Wk    = (const float*)d_in[3];
    const float* Wv    = (const float*)d_in[4];
    const float* bv    = (const float*)d_in[5];
    const float* Wt    = (const float*)d_in[6];
    const float* bt    = (const float*)d_in[7];
    const float* gamma = (const float*)d_in[8];
    const float* beta  = (const float*)d_in[9];
    const float* rmean = (const float*)d_in[10];
    const float* rvar  = (const float*)d_in[11];
    float* out = (float*)d_out;
    float* ws  = (float*)d_ws;

    float* x2   = ws + OFF_X2;
    float* yb   = ws + OFF_Y;
    u16*   bf   = (u16*)(ws + OFF_BF16);
    u16*   xqT  = bf + UOFF_XQT;
    u16*   xkT  = bf + UOFF_XKT;
    u16*   xv   = bf + UOFF_XV;
    float* rmax = ws + OFF_RMAX;
    float* rsum = ws + OFF_RSUM;
    float* sb   = ws + OFF_S;

    dim3 blk(256);
    conv_qk_kernel<<<dim3(NN/256, C2/8, BB), blk, 0, stream>>>(q, Wq, xqT);
    conv_qk_kernel<<<dim3(NN/256, C2/8, BB), blk, 0, stream>>>(x, Wk, xkT);
    conv_v_bf16_kernel<<<dim3(NN/256, CC/8, BB), blk, 0, stream>>>(q, Wv, bv, xv);
    conv_v_f32_kernel<<<dim3(NN/256, CC/8, BB), blk, 0, stream>>>(x, Wv, bv, x2);
    rowstats_mfma<<<dim3(NN/64, BB), blk, 0, stream>>>(xqT, xkT, rmax, rsum);
    pv_mfma<<<dim3(NN/64, BB), blk, 0, stream>>>(xqT, xkT, xv, rmax, rsum, yb, sb);
    dcalc_kernel<<<dim3(4096), blk, 0, stream>>>(x2, yb, sb);
    final_kernel<<<dim3(NN/256, CC/8, BB), blk, 0, stream>>>(yb, x2, Wt, bt, gamma, beta,
                                                             rmean, rvar, out);
}

// Round 5
// 492.063 us; speedup vs baseline: 5.2330x; 1.0456x over previous
//
#include <hip/hip_runtime.h>
#include <hip/hip_bf16.h>
#include <math.h>

#define BB 16
#define CC 256
#define C2 128
#define NN 2048

typedef __attribute__((ext_vector_type(8))) _Float16 f16x8;
typedef __attribute__((ext_vector_type(8))) short bf16x8;
typedef __attribute__((ext_vector_type(16))) float f32x16;
typedef unsigned short u16;

// ---- workspace layout (float offsets) ----
#define OFF_X2   ((size_t)0)           // x2 fp32 [B][C][N]
#define OFF_Y    ((size_t)8388608)     // y  fp32 [B][C][N]
#define OFF_U16  ((size_t)16777216)    // u16 region 1: XQT | XKT | XV
#define UOFF_XQT ((size_t)0)           // fp16 [B][N][C2]
#define UOFF_XKT ((size_t)4194304)     // fp16 [B][N][C2]
#define UOFF_XV  ((size_t)8388608)     // bf16 [B][C][N]
#define OFF_RMAX ((size_t)25165824)
#define OFF_RSUM ((size_t)25198592)
#define OFF_S    ((size_t)25231360)
#define OFF_T16  ((size_t)25264128)    // u16 region 2: QT | XT  (dT aliases whole region)
#define UOFF_QT  ((size_t)0)           // fp16 [B][N][C2]
#define UOFF_XT  ((size_t)4194304)     // fp16 [B][N][C2]
#define OFF_W16  ((size_t)29458432)    // u16: Wq16|Wk16|Wv16|Wt16
#define WOFF_WQ  ((size_t)0)
#define WOFF_WK  ((size_t)16384)
#define WOFF_WV  ((size_t)32768)
#define WOFF_WT  ((size_t)65536)

__device__ __forceinline__ u16 f2h(float f) {
    union { _Float16 h; u16 u; } v; v.h = (_Float16)f;
    return v.u;
}
__device__ __forceinline__ u16 f2bf(float f) {
    union { float f; unsigned u; } v; v.f = f;
    return (u16)((v.u + 0x7fffu + ((v.u >> 16) & 1u)) >> 16);
}
__device__ __forceinline__ float bf2f(u16 h) {
    union { unsigned u; float f; } v; v.u = ((unsigned)h) << 16;
    return v.f;
}

// ---------------- prep: weights -> fp16 ----------------
__global__ __launch_bounds__(256) void prep_w(
    const float* __restrict__ Wq, const float* __restrict__ Wk,
    const float* __restrict__ Wv, const float* __restrict__ Wt,
    u16* __restrict__ w16)
{
    int i = blockIdx.x * 256 + threadIdx.x;   // 131072 total
    float v;
    if (i < 16384)      v = Wq[i];
    else if (i < 32768) v = Wk[i - 16384];
    else if (i < 65536) v = Wv[i - 32768];
    else                v = Wt[i - 65536];
    w16[i] = f2h(v);
}

// ---------------- prep: q,x [b][c][n] f32 -> [b][n][c] fp16 ----------------
// grid (N/64, C2/64, 2B), block 256
__global__ __launch_bounds__(256) void prep_t(
    const float* __restrict__ q, const float* __restrict__ x,
    u16* __restrict__ qT, u16* __restrict__ xT)
{
    __shared__ u16 t_s[64][72];
    int tid = threadIdx.x;
    int n0 = blockIdx.x * 64, c0 = blockIdx.y * 64;
    int zb = blockIdx.z, b = zb >> 1;
    const float* in = (zb & 1) ? x : q;
    u16* out = (zb & 1) ? xT : qT;
    const float* ip = in + ((size_t)b * C2 + c0) * NN + n0;
    int r = tid >> 2, c16 = (tid & 3) * 16;
    #pragma unroll
    for (int j = 0; j < 16; ++j) {
        float v = ip[(size_t)r * NN + c16 + j];
        t_s[c16 + j][r] = f2h(v);
    }
    __syncthreads();
    u16* op = out + ((size_t)b * NN + n0) * C2 + c0;
    int wr = tid >> 2, wc = (tid & 3) * 16;
    *(uint4*)&op[(size_t)wr * C2 + wc]     = *(uint4*)&t_s[wr][wc];
    *(uint4*)&op[(size_t)wr * C2 + wc + 8] = *(uint4*)&t_s[wr][wc + 8];
}

// ---------------- conv qk (MFMA): xqT/xkT [b][n][o] fp16 ----------------
// D[n][o] = sum_c inT[n][c] * W[o][c].  block 64n x 128o, grid (N/64, 1, B)
__global__ __launch_bounds__(256) void conv_qk_mfma(
    const u16* __restrict__ inT, const u16* __restrict__ w16,
    u16* __restrict__ outT)
{
    __shared__ u16 a_s[64 * 136];
    int tid = threadIdx.x, lane = tid & 63, wave = tid >> 6;
    int b = blockIdx.z, n0 = blockIdx.x * 64;
    const u16* ib = inT + (size_t)b * NN * C2;
    for (int i = tid; i < 64 * 16; i += 256) {
        int r = i >> 4, c8 = i & 15;
        *(uint4*)&a_s[r * 136 + c8 * 8] = *(const uint4*)&ib[(size_t)(n0 + r) * C2 + c8 * 8];
    }
    __syncthreads();
    int nsub = wave & 1, oh = wave >> 1;
    int lrow = lane & 31, lk8 = (lane >> 5) * 8;
    f32x16 acc0, acc1;
    #pragma unroll
    for (int r = 0; r < 16; ++r) { acc0[r] = 0.f; acc1[r] = 0.f; }
    const u16* arow = &a_s[(nsub * 32 + lrow) * 136 + lk8];
    const u16* w0 = w16 + (size_t)(oh * 64 + lrow) * C2 + lk8;
    const u16* w1 = w16 + (size_t)(oh * 64 + 32 + lrow) * C2 + lk8;
    #pragma unroll
    for (int kk = 0; kk < 8; ++kk) {
        f16x8 a  = *(const f16x8*)&arow[kk * 16];
        f16x8 b0 = *(const f16x8*)&w0[kk * 16];
        f16x8 b1 = *(const f16x8*)&w1[kk * 16];
        acc0 = __builtin_amdgcn_mfma_f32_32x32x16_f16(a, b0, acc0, 0, 0, 0);
        acc1 = __builtin_amdgcn_mfma_f32_32x32x16_f16(a, b1, acc1, 0, 0, 0);
    }
    #pragma unroll
    for (int r = 0; r < 16; ++r) {
        int ro = (r & 3) + 8 * (r >> 2) + 4 * (lane >> 5);
        size_t row = (size_t)b * NN + n0 + nsub * 32 + ro;
        outT[row * C2 + oh * 64 + lrow]      = f2h(acc0[r]);
        outT[row * C2 + oh * 64 + 32 + lrow] = f2h(acc1[r]);
    }
}

// ---------------- conv v (MFMA): out [b][c][n], bf16 or fp32 ----------------
// D[c][n] = sum_k W[c][k] * inT[n][k] + bias[c].  block 128c x 64n, grid (N/64, 2, B)
__global__ __launch_bounds__(256) void conv_v_mfma(
    const u16* __restrict__ inT, const u16* __restrict__ w16,
    const float* __restrict__ bias, u16* __restrict__ out_bf,
    float* __restrict__ out_f32)
{
    __shared__ u16 b_s[64 * 136];
    int tid = threadIdx.x, lane = tid & 63, wave = tid >> 6;
    int b = blockIdx.z, n0 = blockIdx.x * 64, c0 = blockIdx.y * 128;
    const u16* ib = inT + (size_t)b * NN * C2;
    for (int i = tid; i < 64 * 16; i += 256) {
        int r = i >> 4, c8 = i & 15;
        *(uint4*)&b_s[r * 136 + c8 * 8] = *(const uint4*)&ib[(size_t)(n0 + r) * C2 + c8 * 8];
    }
    __syncthreads();
    int ch = wave >> 1, nsub = wave & 1;
    int lrow = lane & 31, lk8 = (lane >> 5) * 8;
    f32x16 acc0, acc1;
    #pragma unroll
    for (int r = 0; r < 16; ++r) { acc0[r] = 0.f; acc1[r] = 0.f; }
    const u16* brow = &b_s[(nsub * 32 + lrow) * 136 + lk8];
    const u16* a0p = w16 + (size_t)(c0 + ch * 64 + lrow) * C2 + lk8;
    const u16* a1p = w16 + (size_t)(c0 + ch * 64 + 32 + lrow) * C2 + lk8;
    #pragma unroll
    for (int kk = 0; kk < 8; ++kk) {
        f16x8 bb = *(const f16x8*)&brow[kk * 16];
        f16x8 a0 = *(const f16x8*)&a0p[kk * 16];
        f16x8 a1 = *(const f16x8*)&a1p[kk * 16];
        acc0 = __builtin_amdgcn_mfma_f32_32x32x16_f16(a0, bb, acc0, 0, 0, 0);
        acc1 = __builtin_amdgcn_mfma_f32_32x32x16_f16(a1, bb, acc1, 0, 0, 0);
    }
    int n = n0 + nsub * 32 + (lane & 31);
    #pragma unroll
    for (int r = 0; r < 16; ++r) {
        int ro = (r & 3) + 8 * (r >> 2) + 4 * (lane >> 5);
        int cr0 = c0 + ch * 64 + ro, cr1 = cr0 + 32;
        float v0 = acc0[r] + bias[cr0];
        float v1 = acc1[r] + bias[cr1];
        if (out_bf) {
            out_bf[((size_t)b * CC + cr0) * NN + n] = f2bf(v0);
            out_bf[((size_t)b * CC + cr1) * NN + n] = f2bf(v1);
        } else {
            out_f32[((size_t)b * CC + cr0) * NN + n] = v0;
            out_f32[((size_t)b * CC + cr1) * NN + n] = v1;
        }
    }
}

// ---------------- Pass 1: row stats via fp16 MFMA (swizzled, prefetched) ----------------
__global__ __launch_bounds__(256) void rowstats_mfma(
    const u16* __restrict__ xqT, const u16* __restrict__ xkT,
    float* __restrict__ rmax, float* __restrict__ rsum)
{
    __shared__ u16 xq_s[64 * 136];
    __shared__ u16 xk_s[64 * 136];
    __shared__ float Mp[4][32];
    __shared__ float Sp[4][32];
    const int tid  = threadIdx.x;
    int flat = blockIdx.x + gridDim.x * blockIdx.y;   // 512
    int xcd = flat & 7, rank = flat >> 3;
    const int b  = xcd * 2 + (rank >> 5);
    const int n0 = (rank & 31) * 64;
    const int lane = tid & 63;
    const int wave = tid >> 6;
    const u16* xqb = xqT + (size_t)b * NN * C2;
    const u16* xkb = xkT + (size_t)b * NN * C2;

    for (int i = tid; i < 64 * 16; i += 256) {
        int r = i >> 4, c8 = i & 15;
        *(uint4*)&xq_s[r * 136 + c8 * 8] =
            *(const uint4*)&xqb[(size_t)(n0 + r) * C2 + c8 * 8];
    }
    const int msub = wave >> 1, nsub = wave & 1;
    const int lrow = lane & 31;
    const int lk8  = (lane >> 5) * 8;
    float runM = -1e30f, runS = 0.f;

    uint4 pk[4];
    #pragma unroll
    for (int k = 0; k < 4; ++k) {
        int i = tid + 256 * k; int r = i >> 4, c8 = i & 15;
        pk[k] = *(const uint4*)&xkb[(size_t)r * C2 + c8 * 8];
    }
    for (int m0 = 0; m0 < NN; m0 += 64) {
        #pragma unroll
        for (int k = 0; k < 4; ++k) {
            int i = tid + 256 * k; int r = i >> 4, c8 = i & 15;
            *(uint4*)&xk_s[r * 136 + c8 * 8] = pk[k];
        }
        __syncthreads();
        if (m0 + 64 < NN) {
            #pragma unroll
            for (int k = 0; k < 4; ++k) {
                int i = tid + 256 * k; int r = i >> 4, c8 = i & 15;
                pk[k] = *(const uint4*)&xkb[(size_t)(m0 + 64 + r) * C2 + c8 * 8];
            }
        }
        f32x16 e;
        #pragma unroll
        for (int r = 0; r < 16; ++r) e[r] = 0.f;
        const u16* arow = &xk_s[(msub * 32 + lrow) * 136 + lk8];
        const u16* brow = &xq_s[(nsub * 32 + lrow) * 136 + lk8];
        #pragma unroll
        for (int kk = 0; kk < 8; ++kk) {
            f16x8 a  = *(const f16x8*)&arow[kk * 16];
            f16x8 bb = *(const f16x8*)&brow[kk * 16];
            e = __builtin_amdgcn_mfma_f32_32x32x16_f16(a, bb, e, 0, 0, 0);
        }
        float tm = e[0];
        #pragma unroll
        for (int r = 1; r < 16; ++r) tm = fmaxf(tm, e[r]);
        float newM = fmaxf(runM, tm);
        float sc = __expf(runM - newM);
        float ts = 0.f;
        #pragma unroll
        for (int r = 0; r < 16; ++r) ts += __expf(e[r] - newM);
        runS = runS * sc + ts;
        runM = newM;
        __syncthreads();
    }
    float oM = __shfl_xor(runM, 32, 64);
    float oS = __shfl_xor(runS, 32, 64);
    float M2 = fmaxf(runM, oM);
    float S2 = runS * __expf(runM - M2) + oS * __expf(oM - M2);
    if (lane < 32) { Mp[wave][lane] = M2; Sp[wave][lane] = S2; }
    __syncthreads();
    if (tid < 64) {
        int ns = tid >> 5, li = tid & 31;
        float Ma = Mp[ns][li], Mb = Mp[ns + 2][li];
        float Mf = fmaxf(Ma, Mb);
        float Sf = Sp[ns][li] * __expf(Ma - Mf) + Sp[ns + 2][li] * __expf(Mb - Mf);
        rmax[(size_t)b * NN + n0 + tid] = Mf;
        rsum[(size_t)b * NN + n0 + tid] = Sf;
    }
}

// ---------------- Pass 2: PV (swizzled, prefetched) ----------------
__global__ __launch_bounds__(256) void pv_mfma(
    const u16* __restrict__ xqT, const u16* __restrict__ xkT,
    const u16* __restrict__ xv, const float* __restrict__ rmax,
    const float* __restrict__ rsum, float* __restrict__ y,
    float* __restrict__ s_out)
{
    __shared__ u16 xk_s[64 * 136];   // [m][c]  fp16
    __shared__ u16 xq_s[64 * 136];   // [n][c]  fp16
    __shared__ u16 xv_s[256 * 72];   // [c][n]  bf16
    __shared__ u16 p_s[64 * 72];     // [m][n]  bf16
    __shared__ float M_s[64];
    __shared__ float Si_s[64];
    const int tid  = threadIdx.x;
    int flat = blockIdx.x + gridDim.x * blockIdx.y;
    int xcd = flat & 7, rank = flat >> 3;
    const int b  = xcd * 2 + (rank >> 5);
    const int m0 = (rank & 31) * 64;
    const int lane = tid & 63;
    const int wave = tid >> 6;
    const u16* xqb = xqT + (size_t)b * NN * C2;
    const u16* xkb = xkT + (size_t)b * NN * C2;
    const u16* xvb = xv + (size_t)b * CC * NN;

    for (int i = tid; i < 64 * 16; i += 256) {
        int r = i >> 4, c8 = i & 15;
        *(uint4*)&xk_s[r * 136 + c8 * 8] =
            *(const uint4*)&xkb[(size_t)(m0 + r) * C2 + c8 * 8];
    }
    f32x16 acc00, acc01, acc10, acc11;
    #pragma unroll
    for (int r = 0; r < 16; ++r)
        { acc00[r] = 0.f; acc01[r] = 0.f; acc10[r] = 0.f; acc11[r] = 0.f; }
    float s_reg = 0.f;
    const int lrow  = lane & 31;
    const int lk8   = (lane >> 5) * 8;
    const int emsub = wave & 1, ensub = wave >> 1;
    const int cbase = wave * 64;
    const int smq   = tid & 63, sq = tid >> 6;

    uint4 pq[4], px[8];
    float pM = 0.f, pS = 1.f;
    #pragma unroll
    for (int k = 0; k < 4; ++k) {
        int i = tid + 256 * k; int r = i >> 4, c8 = i & 15;
        pq[k] = *(const uint4*)&xqb[(size_t)r * C2 + c8 * 8];
    }
    #pragma unroll
    for (int k = 0; k < 8; ++k) {
        int i = tid + 256 * k; int c = i >> 3, k8 = i & 7;
        px[k] = *(const uint4*)&xvb[(size_t)c * NN + k8 * 8];
    }
    if (tid < 64) { pM = rmax[(size_t)b * NN + tid]; pS = rsum[(size_t)b * NN + tid]; }

    for (int n0 = 0; n0 < NN; n0 += 64) {
        #pragma unroll
        for (int k = 0; k < 4; ++k) {
            int i = tid + 256 * k; int r = i >> 4, c8 = i & 15;
            *(uint4*)&xq_s[r * 136 + c8 * 8] = pq[k];
        }
        #pragma unroll
        for (int k = 0; k < 8; ++k) {
            int i = tid + 256 * k; int c = i >> 3, k8 = i & 7;
            *(uint4*)&xv_s[c * 72 + k8 * 8] = px[k];
        }
        if (tid < 64) { M_s[tid] = pM; Si_s[tid] = 1.f / pS; }
        __syncthreads();
        if (n0 + 64 < NN) {
            #pragma unroll
            for (int k = 0; k < 4; ++k) {
                int i = tid + 256 * k; int r = i >> 4, c8 = i & 15;
                pq[k] = *(const uint4*)&xqb[(size_t)(n0 + 64 + r) * C2 + c8 * 8];
            }
            #pragma unroll
            for (int k = 0; k < 8; ++k) {
                int i = tid + 256 * k; int c = i >> 3, k8 = i & 7;
                px[k] = *(const uint4*)&xvb[(size_t)c * NN + n0 + 64 + k8 * 8];
            }
            if (tid < 64) {
                pM = rmax[(size_t)b * NN + n0 + 64 + tid];
                pS = rsum[(size_t)b * NN + n0 + 64 + tid];
            }
        }
        // energy subtile (32x32) per wave — fp16, same fragments/order as pass 1
        f32x16 e;
        #pragma unroll
        for (int r = 0; r < 16; ++r) e[r] = 0.f;
        {
            const u16* arow = &xk_s[(emsub * 32 + lrow) * 136 + lk8];
            const u16* brow = &xq_s[(ensub * 32 + lrow) * 136 + lk8];
            #pragma unroll
            for (int kk = 0; kk < 8; ++kk) {
                f16x8 a  = *(const f16x8*)&arow[kk * 16];
                f16x8 bb = *(const f16x8*)&brow[kk * 16];
                e = __builtin_amdgcn_mfma_f32_32x32x16_f16(a, bb, e, 0, 0, 0);
            }
        }
        {
            int nl = ensub * 32 + lrow;
            float Mn = M_s[nl], Si = Si_s[nl];
            int mbase = emsub * 32 + 4 * (lane >> 5);
            #pragma unroll
            for (int r = 0; r < 16; ++r) {
                int ml = mbase + (r & 3) + 8 * (r >> 2);
                float p = __expf(e[r] - Mn) * Si;
                p_s[ml * 72 + nl] = f2bf(p);
            }
        }
        __syncthreads();
        {
            const u16* pr = &p_s[smq * 72 + sq * 16];
            float ss = 0.f;
            #pragma unroll
            for (int j = 0; j < 16; ++j) ss += bf2f(pr[j]);
            s_reg += ss;
        }
        {
            const u16* a0r = &xv_s[(cbase + lrow) * 72 + lk8];
            const u16* a1r = &xv_s[(cbase + 32 + lrow) * 72 + lk8];
            const u16* b0r = &p_s[lrow * 72 + lk8];
            const u16* b1r = &p_s[(32 + lrow) * 72 + lk8];
            #pragma unroll
            for (int kk = 0; kk < 4; ++kk) {
                bf16x8 a0 = *(const bf16x8*)&a0r[kk * 16];
                bf16x8 a1 = *(const bf16x8*)&a1r[kk * 16];
                bf16x8 b0 = *(const bf16x8*)&b0r[kk * 16];
                bf16x8 b1 = *(const bf16x8*)&b1r[kk * 16];
                acc00 = __builtin_amdgcn_mfma_f32_32x32x16_bf16(a0, b0, acc00, 0, 0, 0);
                acc01 = __builtin_amdgcn_mfma_f32_32x32x16_bf16(a0, b1, acc01, 0, 0, 0);
                acc10 = __builtin_amdgcn_mfma_f32_32x32x16_bf16(a1, b0, acc10, 0, 0, 0);
                acc11 = __builtin_amdgcn_mfma_f32_32x32x16_bf16(a1, b1, acc11, 0, 0, 0);
            }
        }
        __syncthreads();
    }
    float* yb = y + (size_t)b * CC * NN;
    #pragma unroll
    for (int r = 0; r < 16; ++r) {
        int ro = (r & 3) + 8 * (r >> 2) + 4 * (lane >> 5);
        yb[(size_t)(cbase + ro) * NN + m0 + lrow]           = acc00[r];
        yb[(size_t)(cbase + ro) * NN + m0 + 32 + lrow]      = acc01[r];
        yb[(size_t)(cbase + 32 + ro) * NN + m0 + lrow]      = acc10[r];
        yb[(size_t)(cbase + 32 + ro) * NN + m0 + 32 + lrow] = acc11[r];
    }
    __syncthreads();
    float* s_part = (float*)p_s;
    s_part[(tid & 63) * 4 + (tid >> 6)] = s_reg;
    __syncthreads();
    if (tid < 64) {
        float ss = s_part[tid * 4] + s_part[tid * 4 + 1] +
                   s_part[tid * 4 + 2] + s_part[tid * 4 + 3];
        s_out[(size_t)b * NN + m0 + tid] = ss;
    }
}

// ---------------- dcalc + transpose: dT[b][n][c] fp16 ----------------
// grid (N/64, C/64, B), block 256
__global__ __launch_bounds__(256) void dcalc_t(
    const float* __restrict__ y, const float* __restrict__ x2,
    const float* __restrict__ s, u16* __restrict__ dT)
{
    __shared__ u16 t_s[64][72];
    __shared__ float sinv[64];
    int tid = threadIdx.x;
    int n0 = blockIdx.x * 64, c0 = blockIdx.y * 64, b = blockIdx.z;
    if (tid < 64) sinv[tid] = 1.f / (1e-9f + s[(size_t)b * NN + n0 + tid]);
    __syncthreads();
    int r = tid >> 2, c16 = (tid & 3) * 16;
    const float* yp = y  + ((size_t)b * CC + c0 + r) * NN + n0 + c16;
    const float* xp = x2 + ((size_t)b * CC + c0 + r) * NN + n0 + c16;
    #pragma unroll
    for (int j = 0; j < 16; ++j) {
        float d = xp[j] - yp[j] * sinv[c16 + j];
        t_s[c16 + j][r] = f2h(d);
    }
    __syncthreads();
    u16* op = dT + ((size_t)b * NN + n0) * CC + c0;
    int wr = tid >> 2, wc = (tid & 3) * 16;
    *(uint4*)&op[(size_t)wr * CC + wc]     = *(uint4*)&t_s[wr][wc];
    *(uint4*)&op[(size_t)wr * CC + wc + 8] = *(uint4*)&t_s[wr][wc + 8];
}

// ---------------- final (MFMA): out = relu(BN(Wt·d + bt)) + x2 ----------------
// D[o][n] = sum_c Wt[o][c] dT[n][c].  block 128o x 64n, grid (N/64, 2, B)
__global__ __launch_bounds__(256) void final_mfma(
    const u16* __restrict__ dT, const u16* __restrict__ wt16,
    const float* __restrict__ bt, const float* __restrict__ gamma,
    const float* __restrict__ beta, const float* __restrict__ rmean,
    const float* __restrict__ rvar, const float* __restrict__ x2,
    float* __restrict__ out)
{
    __shared__ u16 b_s[64 * 264];
    __shared__ float inv_s[128], add_s[128];
    int tid = threadIdx.x, lane = tid & 63, wave = tid >> 6;
    int n0 = blockIdx.x * 64, o0 = blockIdx.y * 128, b = blockIdx.z;
    for (int i = tid; i < 64 * 32; i += 256) {
        int r = i >> 5, c8 = i & 31;
        *(uint4*)&b_s[r * 264 + c8 * 8] =
            *(const uint4*)&dT[((size_t)b * NN + n0 + r) * CC + c8 * 8];
    }
    if (tid < 128) {
        int o = o0 + tid;
        float iv = gamma[o] * rsqrtf(rvar[o] + 1e-5f);
        inv_s[tid] = iv;
        add_s[tid] = bt[o] * iv + beta[o] - rmean[o] * iv;
    }
    __syncthreads();
    int oh = wave >> 1, nsub = wave & 1;
    int lrow = lane & 31, lk8 = (lane >> 5) * 8;
    f32x16 acc0, acc1;
    #pragma unroll
    for (int r = 0; r < 16; ++r) { acc0[r] = 0.f; acc1[r] = 0.f; }
    const u16* brow = &b_s[(nsub * 32 + lrow) * 264 + lk8];
    const u16* a0p = wt16 + (size_t)(o0 + oh * 64 + lrow) * CC + lk8;
    const u16* a1p = wt16 + (size_t)(o0 + oh * 64 + 32 + lrow) * CC + lk8;
    #pragma unroll
    for (int kk = 0; kk < 16; ++kk) {
        f16x8 bb = *(const f16x8*)&brow[kk * 16];
        f16x8 a0 = *(const f16x8*)&a0p[kk * 16];
        f16x8 a1 = *(const f16x8*)&a1p[kk * 16];
        acc0 = __builtin_amdgcn_mfma_f32_32x32x16_f16(a0, bb, acc0, 0, 0, 0);
        acc1 = __builtin_amdgcn_mfma_f32_32x32x16_f16(a1, bb, acc1, 0, 0, 0);
    }
    int n = n0 + nsub * 32 + (lane & 31);
    #pragma unroll
    for (int r = 0; r < 16; ++r) {
        int ro = (r & 3) + 8 * (r >> 2) + 4 * (lane >> 5);
        int ol0 = oh * 64 + ro, ol1 = ol0 + 32;
        float t0 = acc0[r] * inv_s[ol0] + add_s[ol0];
        float t1 = acc1[r] * inv_s[ol1] + add_s[ol1];
        size_t i0 = ((size_t)b * CC + o0 + ol0) * NN + n;
        size_t i1 = ((size_t)b * CC + o0 + ol1) * NN + n;
        out[i0] = fmaxf(t0, 0.f) + x2[i0];
        out[i1] = fmaxf(t1, 0.f) + x2[i1];
    }
}

extern "C" void kernel_launch(void* const* d_in, const int* in_sizes, int n_in,
                              void* d_out, int out_size, void* d_ws, size_t ws_size,
                              hipStream_t stream)
{
    const float* q     = (const float*)d_in[0];
    const float* x     = (const float*)d_in[1];
    const float* Wq    = (const float*)d_in[2];
    const float* Wk    = (const float*)d_in[3];
    const float* Wv    = (const float*)d_in[4];
    const float* bv    = (const float*)d_in[5];
    const float* Wt    = (const float*)d_in[6];
    const float* bt    = (const float*)d_in[7];
    const float* gamma = (const float*)d_in[8];
    const float* beta  = (const float*)d_in[9];
    const float* rmean = (const float*)d_in[10];
    const float* rvar  = (const float*)d_in[11];
    float* out = (float*)d_out;
    float* ws  = (float*)d_ws;

    float* x2   = ws + OFF_X2;
    float* yb   = ws + OFF_Y;
    u16*   u1   = (u16*)(ws + OFF_U16);
    u16*   xqT  = u1 + UOFF_XQT;
    u16*   xkT  = u1 + UOFF_XKT;
    u16*   xv   = u1 + UOFF_XV;
    float* rmax = ws + OFF_RMAX;
    float* rsum = ws + OFF_RSUM;
    float* sb   = ws + OFF_S;
    u16*   u2   = (u16*)(ws + OFF_T16);
    u16*   qT   = u2 + UOFF_QT;
    u16*   xT   = u2 + UOFF_XT;
    u16*   dT   = u2;                 // aliases qT+xT (dead after convs)
    u16*   w16  = (u16*)(ws + OFF_W16);

    dim3 blk(256);
    prep_w<<<dim3(512), blk, 0, stream>>>(Wq, Wk, Wv, Wt, w16);
    prep_t<<<dim3(NN/64, C2/64, 2*BB), blk, 0, stream>>>(q, x, qT, xT);
    conv_qk_mfma<<<dim3(NN/64, 1, BB), blk, 0, stream>>>(qT, w16 + WOFF_WQ, xqT);
    conv_qk_mfma<<<dim3(NN/64, 1, BB), blk, 0, stream>>>(xT, w16 + WOFF_WK, xkT);
    conv_v_mfma<<<dim3(NN/64, 2, BB), blk, 0, stream>>>(qT, w16 + WOFF_WV, bv, xv, nullptr);
    conv_v_mfma<<<dim3(NN/64, 2, BB), blk, 0, stream>>>(xT, w16 + WOFF_WV, bv, nullptr, x2);
    rowstats_mfma<<<dim3(NN/64, BB), blk, 0, stream>>>(xqT, xkT, rmax, rsum);
    pv_mfma<<<dim3(NN/64, BB), blk, 0, stream>>>(xqT, xkT, xv, rmax, rsum, yb, sb);
    dcalc_t<<<dim3(NN/64, CC/64, BB), blk, 0, stream>>>(yb, x2, sb, dT);
    final_mfma<<<dim3(NN/64, 2, BB), blk, 0, stream>>>(dT, w16 + WOFF_WT, bt, gamma,
                                                       beta, rmean, rvar, x2, out);
}

// Round 6
// 347.563 us; speedup vs baseline: 7.4086x; 1.4157x over previous
//
#include <hip/hip_runtime.h>
#include <hip/hip_bf16.h>
#include <math.h>

#define BB 16
#define CC 256
#define C2 128
#define NN 2048

typedef __attribute__((ext_vector_type(8))) _Float16 f16x8;
typedef __attribute__((ext_vector_type(8))) short bf16x8;
typedef __attribute__((ext_vector_type(16))) float f32x16;
typedef unsigned short u16;

// ---- workspace layout (float offsets) ----
#define OFF_X2   ((size_t)0)           // x2 fp32 [B][C][N]
#define OFF_U16  ((size_t)16777216)    // u16 region 1: XQT | XKT | XV
#define UOFF_XQT ((size_t)0)           // fp16 [B][N][C2]
#define UOFF_XKT ((size_t)4194304)     // fp16 [B][N][C2]
#define UOFF_XV  ((size_t)8388608)     // bf16 [B][C][N]
#define OFF_RMAX ((size_t)25165824)
#define OFF_RSUM ((size_t)25198592)
#define OFF_T16  ((size_t)25264128)    // u16 region 2: QT | XT  (dT aliases whole region)
#define UOFF_QT  ((size_t)0)           // fp16 [B][N][C2]
#define UOFF_XT  ((size_t)4194304)     // fp16 [B][N][C2]
#define OFF_W16  ((size_t)29458432)    // u16: Wq16|Wk16|Wv16|Wt16
#define WOFF_WQ  ((size_t)0)
#define WOFF_WK  ((size_t)16384)
#define WOFF_WV  ((size_t)32768)
#define WOFF_WT  ((size_t)65536)

__device__ __forceinline__ u16 f2h(float f) {
    union { _Float16 h; u16 u; } v; v.h = (_Float16)f;
    return v.u;
}
__device__ __forceinline__ u16 f2bf(float f) {
    union { float f; unsigned u; } v; v.f = f;
    return (u16)((v.u + 0x7fffu + ((v.u >> 16) & 1u)) >> 16);
}
__device__ __forceinline__ float bf2f(u16 h) {
    union { unsigned u; float f; } v; v.u = ((unsigned)h) << 16;
    return v.f;
}

// ---------------- prep: weights -> fp16 ----------------
__global__ __launch_bounds__(256) void prep_w(
    const float* __restrict__ Wq, const float* __restrict__ Wk,
    const float* __restrict__ Wv, const float* __restrict__ Wt,
    u16* __restrict__ w16)
{
    int i = blockIdx.x * 256 + threadIdx.x;   // 131072 total
    float v;
    if (i < 16384)      v = Wq[i];
    else if (i < 32768) v = Wk[i - 16384];
    else if (i < 65536) v = Wv[i - 32768];
    else                v = Wt[i - 65536];
    w16[i] = f2h(v);
}

// ---------------- prep: q,x [b][c][n] f32 -> [b][n][c] fp16 ----------------
// grid (N/64, C2/64, 2B), block 256
__global__ __launch_bounds__(256) void prep_t(
    const float* __restrict__ q, const float* __restrict__ x,
    u16* __restrict__ qT, u16* __restrict__ xT)
{
    __shared__ u16 t_s[64][72];
    int tid = threadIdx.x;
    int n0 = blockIdx.x * 64, c0 = blockIdx.y * 64;
    int zb = blockIdx.z, b = zb >> 1;
    const float* in = (zb & 1) ? x : q;
    u16* out = (zb & 1) ? xT : qT;
    const float* ip = in + ((size_t)b * C2 + c0) * NN + n0;
    int r = tid >> 2, c16 = (tid & 3) * 16;
    #pragma unroll
    for (int j = 0; j < 16; ++j) {
        float v = ip[(size_t)r * NN + c16 + j];
        t_s[c16 + j][r] = f2h(v);
    }
    __syncthreads();
    u16* op = out + ((size_t)b * NN + n0) * C2 + c0;
    int wr = tid >> 2, wc = (tid & 3) * 16;
    *(uint4*)&op[(size_t)wr * C2 + wc]     = *(uint4*)&t_s[wr][wc];
    *(uint4*)&op[(size_t)wr * C2 + wc + 8] = *(uint4*)&t_s[wr][wc + 8];
}

// ---------------- conv qk (MFMA): xqT/xkT [b][n][o] fp16 ----------------
// D[n][o] = sum_c inT[n][c] * W[o][c].  block 64n x 128o, grid (N/64, 1, B)
__global__ __launch_bounds__(256) void conv_qk_mfma(
    const u16* __restrict__ inT, const u16* __restrict__ w16,
    u16* __restrict__ outT)
{
    __shared__ u16 a_s[64 * 136];
    int tid = threadIdx.x, lane = tid & 63, wave = tid >> 6;
    int b = blockIdx.z, n0 = blockIdx.x * 64;
    const u16* ib = inT + (size_t)b * NN * C2;
    for (int i = tid; i < 64 * 16; i += 256) {
        int r = i >> 4, c8 = i & 15;
        *(uint4*)&a_s[r * 136 + c8 * 8] = *(const uint4*)&ib[(size_t)(n0 + r) * C2 + c8 * 8];
    }
    __syncthreads();
    int nsub = wave & 1, oh = wave >> 1;
    int lrow = lane & 31, lk8 = (lane >> 5) * 8;
    f32x16 acc0, acc1;
    #pragma unroll
    for (int r = 0; r < 16; ++r) { acc0[r] = 0.f; acc1[r] = 0.f; }
    const u16* arow = &a_s[(nsub * 32 + lrow) * 136 + lk8];
    const u16* w0 = w16 + (size_t)(oh * 64 + lrow) * C2 + lk8;
    const u16* w1 = w16 + (size_t)(oh * 64 + 32 + lrow) * C2 + lk8;
    #pragma unroll
    for (int kk = 0; kk < 8; ++kk) {
        f16x8 a  = *(const f16x8*)&arow[kk * 16];
        f16x8 b0 = *(const f16x8*)&w0[kk * 16];
        f16x8 b1 = *(const f16x8*)&w1[kk * 16];
        acc0 = __builtin_amdgcn_mfma_f32_32x32x16_f16(a, b0, acc0, 0, 0, 0);
        acc1 = __builtin_amdgcn_mfma_f32_32x32x16_f16(a, b1, acc1, 0, 0, 0);
    }
    #pragma unroll
    for (int r = 0; r < 16; ++r) {
        int ro = (r & 3) + 8 * (r >> 2) + 4 * (lane >> 5);
        size_t row = (size_t)b * NN + n0 + nsub * 32 + ro;
        outT[row * C2 + oh * 64 + lrow]      = f2h(acc0[r]);
        outT[row * C2 + oh * 64 + 32 + lrow] = f2h(acc1[r]);
    }
}

// ---------------- conv v (MFMA): out [b][c][n], bf16 or fp32 ----------------
// D[c][n] = sum_k W[c][k] * inT[n][k] + bias[c].  block 128c x 64n, grid (N/64, 2, B)
__global__ __launch_bounds__(256) void conv_v_mfma(
    const u16* __restrict__ inT, const u16* __restrict__ w16,
    const float* __restrict__ bias, u16* __restrict__ out_bf,
    float* __restrict__ out_f32)
{
    __shared__ u16 b_s[64 * 136];
    int tid = threadIdx.x, lane = tid & 63, wave = tid >> 6;
    int b = blockIdx.z, n0 = blockIdx.x * 64, c0 = blockIdx.y * 128;
    const u16* ib = inT + (size_t)b * NN * C2;
    for (int i = tid; i < 64 * 16; i += 256) {
        int r = i >> 4, c8 = i & 15;
        *(uint4*)&b_s[r * 136 + c8 * 8] = *(const uint4*)&ib[(size_t)(n0 + r) * C2 + c8 * 8];
    }
    __syncthreads();
    int ch = wave >> 1, nsub = wave & 1;
    int lrow = lane & 31, lk8 = (lane >> 5) * 8;
    f32x16 acc0, acc1;
    #pragma unroll
    for (int r = 0; r < 16; ++r) { acc0[r] = 0.f; acc1[r] = 0.f; }
    const u16* brow = &b_s[(nsub * 32 + lrow) * 136 + lk8];
    const u16* a0p = w16 + (size_t)(c0 + ch * 64 + lrow) * C2 + lk8;
    const u16* a1p = w16 + (size_t)(c0 + ch * 64 + 32 + lrow) * C2 + lk8;
    #pragma unroll
    for (int kk = 0; kk < 8; ++kk) {
        f16x8 bb = *(const f16x8*)&brow[kk * 16];
        f16x8 a0 = *(const f16x8*)&a0p[kk * 16];
        f16x8 a1 = *(const f16x8*)&a1p[kk * 16];
        acc0 = __builtin_amdgcn_mfma_f32_32x32x16_f16(a0, bb, acc0, 0, 0, 0);
        acc1 = __builtin_amdgcn_mfma_f32_32x32x16_f16(a1, bb, acc1, 0, 0, 0);
    }
    int n = n0 + nsub * 32 + (lane & 31);
    #pragma unroll
    for (int r = 0; r < 16; ++r) {
        int ro = (r & 3) + 8 * (r >> 2) + 4 * (lane >> 5);
        int cr0 = c0 + ch * 64 + ro, cr1 = cr0 + 32;
        float v0 = acc0[r] + bias[cr0];
        float v1 = acc1[r] + bias[cr1];
        if (out_bf) {
            out_bf[((size_t)b * CC + cr0) * NN + n] = f2bf(v0);
            out_bf[((size_t)b * CC + cr1) * NN + n] = f2bf(v1);
        } else {
            out_f32[((size_t)b * CC + cr0) * NN + n] = v0;
            out_f32[((size_t)b * CC + cr1) * NN + n] = v1;
        }
    }
}

// ---------------- Pass 1: row stats via fp16 MFMA (XCD-swizzled) ----------------
__global__ __launch_bounds__(256) void rowstats_mfma(
    const u16* __restrict__ xqT, const u16* __restrict__ xkT,
    float* __restrict__ rmax, float* __restrict__ rsum)
{
    __shared__ u16 xq_s[64 * 136];
    __shared__ u16 xk_s[64 * 136];
    __shared__ float Mp[4][32];
    __shared__ float Sp[4][32];
    const int tid  = threadIdx.x;
    int flat = blockIdx.x + gridDim.x * blockIdx.y;   // 512
    int xcd = flat & 7, rank = flat >> 3;
    const int b  = xcd * 2 + (rank >> 5);
    const int n0 = (rank & 31) * 64;
    const int lane = tid & 63;
    const int wave = tid >> 6;
    const u16* xqb = xqT + (size_t)b * NN * C2;
    const u16* xkb = xkT + (size_t)b * NN * C2;

    for (int i = tid; i < 64 * 16; i += 256) {
        int r = i >> 4, c8 = i & 15;
        *(uint4*)&xq_s[r * 136 + c8 * 8] =
            *(const uint4*)&xqb[(size_t)(n0 + r) * C2 + c8 * 8];
    }
    const int msub = wave >> 1, nsub = wave & 1;
    const int lrow = lane & 31;
    const int lk8  = (lane >> 5) * 8;
    float runM = -1e30f, runS = 0.f;

    for (int m0 = 0; m0 < NN; m0 += 64) {
        for (int i = tid; i < 64 * 16; i += 256) {
            int r = i >> 4, c8 = i & 15;
            *(uint4*)&xk_s[r * 136 + c8 * 8] =
                *(const uint4*)&xkb[(size_t)(m0 + r) * C2 + c8 * 8];
        }
        __syncthreads();
        f32x16 e;
        #pragma unroll
        for (int r = 0; r < 16; ++r) e[r] = 0.f;
        const u16* arow = &xk_s[(msub * 32 + lrow) * 136 + lk8];
        const u16* brow = &xq_s[(nsub * 32 + lrow) * 136 + lk8];
        #pragma unroll
        for (int kk = 0; kk < 8; ++kk) {
            f16x8 a  = *(const f16x8*)&arow[kk * 16];
            f16x8 bb = *(const f16x8*)&brow[kk * 16];
            e = __builtin_amdgcn_mfma_f32_32x32x16_f16(a, bb, e, 0, 0, 0);
        }
        float tm = e[0];
        #pragma unroll
        for (int r = 1; r < 16; ++r) tm = fmaxf(tm, e[r]);
        float newM = fmaxf(runM, tm);
        float sc = __expf(runM - newM);
        float ts = 0.f;
        #pragma unroll
        for (int r = 0; r < 16; ++r) ts += __expf(e[r] - newM);
        runS = runS * sc + ts;
        runM = newM;
        __syncthreads();
    }
    float oM = __shfl_xor(runM, 32, 64);
    float oS = __shfl_xor(runS, 32, 64);
    float M2 = fmaxf(runM, oM);
    float S2 = runS * __expf(runM - M2) + oS * __expf(oM - M2);
    if (lane < 32) { Mp[wave][lane] = M2; Sp[wave][lane] = S2; }
    __syncthreads();
    if (tid < 64) {
        int ns = tid >> 5, li = tid & 31;
        float Ma = Mp[ns][li], Mb = Mp[ns + 2][li];
        float Mf = fmaxf(Ma, Mb);
        float Sf = Sp[ns][li] * __expf(Ma - Mf) + Sp[ns + 2][li] * __expf(Mb - Mf);
        rmax[(size_t)b * NN + n0 + tid] = Mf;
        rsum[(size_t)b * NN + n0 + tid] = Sf;
    }
}

// ---------------- Pass 2: PV + fused dcalc (XCD-swizzled, direct staging) ----------------
// Per 64-col m-tile: recompute E, P=exp(e-M)/S (bf16), y = xv·P via MFMA, s=colsum(P).
// Epilogue (fused dcalc): d = x2 - y/(1e-9+s), LDS-transpose, store dT fp16 [b][n][c].
__global__ __launch_bounds__(256) void pv_mfma(
    const u16* __restrict__ xqT, const u16* __restrict__ xkT,
    const u16* __restrict__ xv, const float* __restrict__ rmax,
    const float* __restrict__ rsum, const float* __restrict__ x2,
    u16* __restrict__ dT)
{
    __shared__ u16 xk_s[64 * 136];   // [m][c]  fp16
    __shared__ u16 xq_s[64 * 136];   // [n][c]  fp16
    __shared__ u16 xv_s[256 * 72];   // [c][n]  bf16  (reused as dT transpose buf)
    __shared__ u16 p_s[64 * 72];     // [m][n]  bf16  (reused as s_part)
    __shared__ float M_s[64];        // (reused as sinv)
    __shared__ float Si_s[64];
    const int tid  = threadIdx.x;
    int flat = blockIdx.x + gridDim.x * blockIdx.y;
    int xcd = flat & 7, rank = flat >> 3;
    const int b  = xcd * 2 + (rank >> 5);
    const int m0 = (rank & 31) * 64;
    const int lane = tid & 63;
    const int wave = tid >> 6;
    const u16* xqb = xqT + (size_t)b * NN * C2;
    const u16* xkb = xkT + (size_t)b * NN * C2;
    const u16* xvb = xv + (size_t)b * CC * NN;

    for (int i = tid; i < 64 * 16; i += 256) {
        int r = i >> 4, c8 = i & 15;
        *(uint4*)&xk_s[r * 136 + c8 * 8] =
            *(const uint4*)&xkb[(size_t)(m0 + r) * C2 + c8 * 8];
    }
    f32x16 acc00, acc01, acc10, acc11;
    #pragma unroll
    for (int r = 0; r < 16; ++r)
        { acc00[r] = 0.f; acc01[r] = 0.f; acc10[r] = 0.f; acc11[r] = 0.f; }
    float s_reg = 0.f;
    const int lrow  = lane & 31;
    const int lk8   = (lane >> 5) * 8;
    const int emsub = wave & 1, ensub = wave >> 1;
    const int cbase = wave * 64;
    const int smq   = tid & 63, sq = tid >> 6;

    for (int n0 = 0; n0 < NN; n0 += 64) {
        for (int i = tid; i < 64 * 16; i += 256) {
            int r = i >> 4, c8 = i & 15;
            *(uint4*)&xq_s[r * 136 + c8 * 8] =
                *(const uint4*)&xqb[(size_t)(n0 + r) * C2 + c8 * 8];
        }
        for (int i = tid; i < 256 * 8; i += 256) {
            int c = i >> 3, k8 = i & 7;
            *(uint4*)&xv_s[c * 72 + k8 * 8] =
                *(const uint4*)&xvb[(size_t)c * NN + n0 + k8 * 8];
        }
        if (tid < 64) {
            M_s[tid]  = rmax[(size_t)b * NN + n0 + tid];
            Si_s[tid] = 1.f / rsum[(size_t)b * NN + n0 + tid];
        }
        __syncthreads();
        // energy subtile (32x32) per wave — fp16, same fragments/order as pass 1
        f32x16 e;
        #pragma unroll
        for (int r = 0; r < 16; ++r) e[r] = 0.f;
        {
            const u16* arow = &xk_s[(emsub * 32 + lrow) * 136 + lk8];
            const u16* brow = &xq_s[(ensub * 32 + lrow) * 136 + lk8];
            #pragma unroll
            for (int kk = 0; kk < 8; ++kk) {
                f16x8 a  = *(const f16x8*)&arow[kk * 16];
                f16x8 bb = *(const f16x8*)&brow[kk * 16];
                e = __builtin_amdgcn_mfma_f32_32x32x16_f16(a, bb, e, 0, 0, 0);
            }
        }
        {
            int nl = ensub * 32 + lrow;
            float Mn = M_s[nl], Si = Si_s[nl];
            int mbase = emsub * 32 + 4 * (lane >> 5);
            #pragma unroll
            for (int r = 0; r < 16; ++r) {
                int ml = mbase + (r & 3) + 8 * (r >> 2);
                float p = __expf(e[r] - Mn) * Si;
                p_s[ml * 72 + nl] = f2bf(p);
            }
        }
        __syncthreads();
        // colsum partial (reads the same bf16 P that PV consumes)
        {
            const u16* pr = &p_s[smq * 72 + sq * 16];
            float ss = 0.f;
            #pragma unroll
            for (int j = 0; j < 16; ++j) ss += bf2f(pr[j]);
            s_reg += ss;
        }
        // PV: per wave, c-rows [cbase, cbase+64), both 32-col m-subtiles — bf16 MFMA
        {
            const u16* a0r = &xv_s[(cbase + lrow) * 72 + lk8];
            const u16* a1r = &xv_s[(cbase + 32 + lrow) * 72 + lk8];
            const u16* b0r = &p_s[lrow * 72 + lk8];
            const u16* b1r = &p_s[(32 + lrow) * 72 + lk8];
            #pragma unroll
            for (int kk = 0; kk < 4; ++kk) {
                bf16x8 a0 = *(const bf16x8*)&a0r[kk * 16];
                bf16x8 a1 = *(const bf16x8*)&a1r[kk * 16];
                bf16x8 b0 = *(const bf16x8*)&b0r[kk * 16];
                bf16x8 b1 = *(const bf16x8*)&b1r[kk * 16];
                acc00 = __builtin_amdgcn_mfma_f32_32x32x16_bf16(a0, b0, acc00, 0, 0, 0);
                acc01 = __builtin_amdgcn_mfma_f32_32x32x16_bf16(a0, b1, acc01, 0, 0, 0);
                acc10 = __builtin_amdgcn_mfma_f32_32x32x16_bf16(a1, b0, acc10, 0, 0, 0);
                acc11 = __builtin_amdgcn_mfma_f32_32x32x16_bf16(a1, b1, acc11, 0, 0, 0);
            }
        }
        __syncthreads();
    }
    // ---- fused dcalc epilogue ----
    // 1) finalize column sums s[m] for this m-tile
    float* s_part = (float*)p_s;            // p_s dead after loop
    s_part[smq * 4 + sq] = s_reg;
    __syncthreads();
    float* sinv = M_s;                      // M_s dead after loop
    if (tid < 64) {
        float ss = s_part[tid * 4] + s_part[tid * 4 + 1] +
                   s_part[tid * 4 + 2] + s_part[tid * 4 + 3];
        sinv[tid] = 1.f / (1e-9f + ss);
    }
    __syncthreads();
    // 2) d = x2 - y * sinv[m], as fp16 into LDS transpose buffer dts[m][c]
    u16* dts = xv_s;                        // 64 x 264 = 33.8 KB <= 36.8 KB
    const float* x2b = x2 + (size_t)b * CC * NN;
    float si0 = sinv[lrow], si1 = sinv[32 + lrow];
    #pragma unroll
    for (int r = 0; r < 16; ++r) {
        int ro = (r & 3) + 8 * (r >> 2) + 4 * (lane >> 5);
        int c0r = cbase + ro, c1r = cbase + 32 + ro;
        float d00 = x2b[(size_t)c0r * NN + m0 + lrow]      - acc00[r] * si0;
        float d01 = x2b[(size_t)c0r * NN + m0 + 32 + lrow] - acc01[r] * si1;
        float d10 = x2b[(size_t)c1r * NN + m0 + lrow]      - acc10[r] * si0;
        float d11 = x2b[(size_t)c1r * NN + m0 + 32 + lrow] - acc11[r] * si1;
        dts[lrow * 264 + c0r]        = f2h(d00);
        dts[(32 + lrow) * 264 + c0r] = f2h(d01);
        dts[lrow * 264 + c1r]        = f2h(d10);
        dts[(32 + lrow) * 264 + c1r] = f2h(d11);
    }
    __syncthreads();
    // 3) coalesced store: dT[b][m0+r][c], r in [0,64), c in [0,256)
    u16* op = dT + ((size_t)b * NN + m0) * CC;
    for (int i = tid; i < 64 * 32; i += 256) {
        int r = i >> 5, c8 = i & 31;
        *(uint4*)&op[(size_t)r * CC + c8 * 8] = *(uint4*)&dts[r * 264 + c8 * 8];
    }
}

// ---------------- final (MFMA): out = relu(BN(Wt·d + bt)) + x2 ----------------
// D[o][n] = sum_c Wt[o][c] dT[n][c].  block 128o x 64n, grid (N/64, 2, B)
__global__ __launch_bounds__(256) void final_mfma(
    const u16* __restrict__ dT, const u16* __restrict__ wt16,
    const float* __restrict__ bt, const float* __restrict__ gamma,
    const float* __restrict__ beta, const float* __restrict__ rmean,
    const float* __restrict__ rvar, const float* __restrict__ x2,
    float* __restrict__ out)
{
    __shared__ u16 b_s[64 * 264];
    __shared__ float inv_s[128], add_s[128];
    int tid = threadIdx.x, lane = tid & 63, wave = tid >> 6;
    int n0 = blockIdx.x * 64, o0 = blockIdx.y * 128, b = blockIdx.z;
    for (int i = tid; i < 64 * 32; i += 256) {
        int r = i >> 5, c8 = i & 31;
        *(uint4*)&b_s[r * 264 + c8 * 8] =
            *(const uint4*)&dT[((size_t)b * NN + n0 + r) * CC + c8 * 8];
    }
    if (tid < 128) {
        int o = o0 + tid;
        float iv = gamma[o] * rsqrtf(rvar[o] + 1e-5f);
        inv_s[tid] = iv;
        add_s[tid] = bt[o] * iv + beta[o] - rmean[o] * iv;
    }
    __syncthreads();
    int oh = wave >> 1, nsub = wave & 1;
    int lrow = lane & 31, lk8 = (lane >> 5) * 8;
    f32x16 acc0, acc1;
    #pragma unroll
    for (int r = 0; r < 16; ++r) { acc0[r] = 0.f; acc1[r] = 0.f; }
    const u16* brow = &b_s[(nsub * 32 + lrow) * 264 + lk8];
    const u16* a0p = wt16 + (size_t)(o0 + oh * 64 + lrow) * CC + lk8;
    const u16* a1p = wt16 + (size_t)(o0 + oh * 64 + 32 + lrow) * CC + lk8;
    #pragma unroll
    for (int kk = 0; kk < 16; ++kk) {
        f16x8 bb = *(const f16x8*)&brow[kk * 16];
        f16x8 a0 = *(const f16x8*)&a0p[kk * 16];
        f16x8 a1 = *(const f16x8*)&a1p[kk * 16];
        acc0 = __builtin_amdgcn_mfma_f32_32x32x16_f16(a0, bb, acc0, 0, 0, 0);
        acc1 = __builtin_amdgcn_mfma_f32_32x32x16_f16(a1, bb, acc1, 0, 0, 0);
    }
    int n = n0 + nsub * 32 + (lane & 31);
    #pragma unroll
    for (int r = 0; r < 16; ++r) {
        int ro = (r & 3) + 8 * (r >> 2) + 4 * (lane >> 5);
        int ol0 = oh * 64 + ro, ol1 = ol0 + 32;
        float t0 = acc0[r] * inv_s[ol0] + add_s[ol0];
        float t1 = acc1[r] * inv_s[ol1] + add_s[ol1];
        size_t i0 = ((size_t)b * CC + o0 + ol0) * NN + n;
        size_t i1 = ((size_t)b * CC + o0 + ol1) * NN + n;
        out[i0] = fmaxf(t0, 0.f) + x2[i0];
        out[i1] = fmaxf(t1, 0.f) + x2[i1];
    }
}

extern "C" void kernel_launch(void* const* d_in, const int* in_sizes, int n_in,
                              void* d_out, int out_size, void* d_ws, size_t ws_size,
                              hipStream_t stream)
{
    const float* q     = (const float*)d_in[0];
    const float* x     = (const float*)d_in[1];
    const float* Wq    = (const float*)d_in[2];
    const float* Wk    = (const float*)d_in[3];
    const float* Wv    = (const float*)d_in[4];
    const float* bv    = (const float*)d_in[5];
    const float* Wt    = (const float*)d_in[6];
    const float* bt    = (const float*)d_in[7];
    const float* gamma = (const float*)d_in[8];
    const float* beta  = (const float*)d_in[9];
    const float* rmean = (const float*)d_in[10];
    const float* rvar  = (const float*)d_in[11];
    float* out = (float*)d_out;
    float* ws  = (float*)d_ws;

    float* x2   = ws + OFF_X2;
    u16*   u1   = (u16*)(ws + OFF_U16);
    u16*   xqT  = u1 + UOFF_XQT;
    u16*   xkT  = u1 + UOFF_XKT;
    u16*   xv   = u1 + UOFF_XV;
    float* rmax = ws + OFF_RMAX;
    float* rsum = ws + OFF_RSUM;
    u16*   u2   = (u16*)(ws + OFF_T16);
    u16*   qT   = u2 + UOFF_QT;
    u16*   xT   = u2 + UOFF_XT;
    u16*   dT   = u2;                 // aliases qT+xT (dead after convs)
    u16*   w16  = (u16*)(ws + OFF_W16);

    dim3 blk(256);
    prep_w<<<dim3(512), blk, 0, stream>>>(Wq, Wk, Wv, Wt, w16);
    prep_t<<<dim3(NN/64, C2/64, 2*BB), blk, 0, stream>>>(q, x, qT, xT);
    conv_qk_mfma<<<dim3(NN/64, 1, BB), blk, 0, stream>>>(qT, w16 + WOFF_WQ, xqT);
    conv_qk_mfma<<<dim3(NN/64, 1, BB), blk, 0, stream>>>(xT, w16 + WOFF_WK, xkT);
    conv_v_mfma<<<dim3(NN/64, 2, BB), blk, 0, stream>>>(qT, w16 + WOFF_WV, bv, xv, nullptr);
    conv_v_mfma<<<dim3(NN/64, 2, BB), blk, 0, stream>>>(xT, w16 + WOFF_WV, bv, nullptr, x2);
    rowstats_mfma<<<dim3(NN/64, BB), blk, 0, stream>>>(xqT, xkT, rmax, rsum);
    pv_mfma<<<dim3(NN/64, BB), blk, 0, stream>>>(xqT, xkT, xv, rmax, rsum, x2, dT);
    final_mfma<<<dim3(NN/64, 2, BB), blk, 0, stream>>>(dT, w16 + WOFF_WT, bt, gamma,
                                                       beta, rmean, rvar, x2, out);
}